// Round 1
// baseline (601.849 us; speedup 1.0000x reference)
//
#include <hip/hip_runtime.h>
#include <math.h>

#define DI __device__ __forceinline__

typedef __attribute__((ext_vector_type(8))) short bf16x8;
typedef __attribute__((ext_vector_type(4))) float f32x4;

DI unsigned short f2bf(float f){
  union{float f;unsigned int u;} v; v.f=f;
  unsigned int r = v.u + 0x7FFFu + ((v.u>>16)&1u);
  return (unsigned short)(r>>16);
}

// ---------------- conversion kernels ----------------
__global__ void k_f32_to_bf16(const float* __restrict__ in, unsigned short* __restrict__ out, int n){
  int i = blockIdx.x*256+threadIdx.x;
  if (i<n) out[i]=f2bf(in[i]);
}

// out[n*K+k] = bf16(in[k*N+n])   (weight [K,N] -> B^T [N,K] bf16)
__global__ void k_transpose_bf16(const float* __restrict__ in, unsigned short* __restrict__ out, int K, int N){
  int idx = blockIdx.x*256+threadIdx.x;
  if (idx>=K*N) return;
  int n = idx % N, k = idx / N;
  out[(size_t)n*K+k] = f2bf(in[idx]);
}

// ---------------- matvec (two-stage deterministic) ----------------
// partial: block (jb,ic): cols j4 = (jb*blockDim+tid)*4, rows [ic*chunk, ...)
__global__ void matvec_part_f32(const float* __restrict__ in, const float* __restrict__ W,
                                int nJ, int chunk, float* __restrict__ part){
  int jb = blockIdx.x, ic = blockIdx.y;
  int j4 = (jb*blockDim.x + threadIdx.x)*4;
  int i0 = ic*chunk;
  float a0=0,a1=0,a2=0,a3=0;
  const float* Wp = W + (size_t)i0*nJ + j4;
  for (int i=0;i<chunk;i++){
    float s = in[i0+i];
    float4 wv = *(const float4*)Wp;
    a0 += s*wv.x; a1 += s*wv.y; a2 += s*wv.z; a3 += s*wv.w;
    Wp += nJ;
  }
  float* pp = part + (size_t)ic*nJ + j4;
  pp[0]=a0; pp[1]=a1; pp[2]=a2; pp[3]=a3;
}

__global__ void matvec_part_f64(const float* __restrict__ in, const float* __restrict__ W,
                                int nJ, int chunk, double* __restrict__ part){
  int jb = blockIdx.x, ic = blockIdx.y;
  int j4 = (jb*blockDim.x + threadIdx.x)*4;
  int i0 = ic*chunk;
  double a0=0,a1=0,a2=0,a3=0;
  const float* Wp = W + (size_t)i0*nJ + j4;
  for (int i=0;i<chunk;i++){
    double s = (double)in[i0+i];
    float4 wv = *(const float4*)Wp;
    a0 += s*(double)wv.x; a1 += s*(double)wv.y; a2 += s*(double)wv.z; a3 += s*(double)wv.w;
    Wp += nJ;
  }
  double* pp = part + (size_t)ic*nJ + j4;
  pp[0]=a0; pp[1]=a1; pp[2]=a2; pp[3]=a3;
}

// out[j] = relu(sum_p part[p][j] + bias[j])
__global__ void matvec_reduce_relu(const float* __restrict__ part, int nP, int nJ,
                                   const float* __restrict__ bias, float* __restrict__ out){
  int j = blockIdx.x*blockDim.x + threadIdx.x;
  if (j>=nJ) return;
  float s = 0.f;
  for (int p=0;p<nP;p++) s += part[(size_t)p*nJ+j];
  s += bias[j];
  out[j] = fmaxf(s,0.f);
}

// fc2 reduce: orig logits (fp64 accurate), mask, masked-edge count
__global__ void fc2_reduce(const double* __restrict__ part, int nP, int nJ,
                           const float* __restrict__ bias, float* __restrict__ orig_out,
                           int* __restrict__ mask, int* __restrict__ cnt){
  int j = blockIdx.x*blockDim.x + threadIdx.x;
  if (j>=nJ) return;
  double s = 0.0;
  for (int p=0;p<nP;p++) s += part[(size_t)p*nJ+j];
  s += (double)bias[j];
  float o = (float)s;
  orig_out[j] = o;
  int m = (o > 0.f) ? 1 : 0;   // sigmoid(o)>0.5 <=> o>0
  mask[j] = m;
  unsigned long long b = __ballot(m != 0);
  if ((threadIdx.x&63)==0) atomicAdd(cnt, (int)__popcll(b));
}

// ---------------- bf16 MFMA GEMM, B^T input ----------------
// C[M,N] = A[M,K] * B[K,N], A bf16 row-major, Bt = B^T bf16 row-major [N,K].
// EPI: 0 plain->f32, 1 +bias->f32, 2 relu(+bias)+extra[col]->bf16
template<int BM,int BN,int EPI>
__global__ __launch_bounds__(256) void gemm_bt(const unsigned short* __restrict__ A,
    const unsigned short* __restrict__ Bt, int M, int N, int K,
    const float* __restrict__ bias, const float* __restrict__ extra,
    float* __restrict__ outf, unsigned short* __restrict__ outb){
  __shared__ unsigned short As[BM][32];
  __shared__ unsigned short Bs[BN][32];
  int tid = threadIdx.x;
  int bm = blockIdx.x, bn = blockIdx.y;
  int wave = tid>>6, lane = tid&63;
  int wr = wave>>1, wc = wave&1;
  constexpr int WM = BM/2, WN = BN/2;
  constexpr int FM = WM/16, FN = WN/16;
  f32x4 acc[FM][FN];
  #pragma unroll
  for (int i=0;i<FM;i++)
    #pragma unroll
    for (int j=0;j<FN;j++){ f32x4 z = {0.f,0.f,0.f,0.f}; acc[i][j]=z; }

  int srow = tid>>2;       // 0..63
  int skq  = tid&3;        // 16B quarter of the 32-elem k slice
  constexpr int AR = BM/64, BR = BN/64;

  for (int k0=0;k0<K;k0+=32){
    #pragma unroll
    for (int r=0;r<AR;r++){
      int row = r*64 + srow;
      *(bf16x8*)&As[row][skq*8] = *(const bf16x8*)(A + (size_t)(bm*BM+row)*K + k0 + skq*8);
    }
    #pragma unroll
    for (int r=0;r<BR;r++){
      int row = r*64 + srow;
      *(bf16x8*)&Bs[row][skq*8] = *(const bf16x8*)(Bt + (size_t)(bn*BN+row)*K + k0 + skq*8);
    }
    __syncthreads();
    int lr = lane&15, lk = (lane>>4)*8;
    bf16x8 a[FM], b[FN];
    #pragma unroll
    for (int i=0;i<FM;i++) a[i] = *(const bf16x8*)&As[wr*WM + i*16 + lr][lk];
    #pragma unroll
    for (int j=0;j<FN;j++) b[j] = *(const bf16x8*)&Bs[wc*WN + j*16 + lr][lk];
    #pragma unroll
    for (int i=0;i<FM;i++)
      #pragma unroll
      for (int j=0;j<FN;j++)
        acc[i][j] = __builtin_amdgcn_mfma_f32_16x16x32_bf16(a[i], b[j], acc[i][j], 0,0,0);
    __syncthreads();
  }

  int lr = lane&15, lq = lane>>4;
  #pragma unroll
  for (int i=0;i<FM;i++)
    #pragma unroll
    for (int j=0;j<FN;j++){
      int col = bn*BN + wc*WN + j*16 + lr;
      #pragma unroll
      for (int r=0;r<4;r++){
        int row = bm*BM + wr*WM + i*16 + lq*4 + r;
        float v = acc[i][j][r];
        if constexpr (EPI>=1) v += bias[col];
        if constexpr (EPI==2) v = fmaxf(v,0.f) + extra[col];
        if constexpr (EPI==2) outb[(size_t)row*N+col] = f2bf(v);
        else outf[(size_t)row*N+col] = v;
      }
    }
}

// ---------------- GAT pieces ----------------
// per-node attention dots: als[n,h] = sum_c xp[n,h,c]*asrc[h,c]; same ald.
__global__ __launch_bounds__(256) void gat_al(const float* __restrict__ xp,
    const float* __restrict__ asrc, const float* __restrict__ adst,
    int Hh, int C, float* __restrict__ als, float* __restrict__ ald){
  int n = blockIdx.x, t = threadIdx.x;
  __shared__ float red[8];
  for (int h=0;h<Hh;h++){
    float vs=0.f, vd=0.f;
    for (int c=t;c<C;c+=256){
      float v = xp[((size_t)n*Hh+h)*C + c];
      vs += v*asrc[h*C+c]; vd += v*adst[h*C+c];
    }
    #pragma unroll
    for (int o=32;o>0;o>>=1){ vs += __shfl_down(vs,o); vd += __shfl_down(vd,o); }
    __syncthreads();
    if ((t&63)==0){ red[(t>>6)*2]=vs; red[(t>>6)*2+1]=vd; }
    __syncthreads();
    if (t==0){
      als[n*Hh+h]=red[0]+red[2]+red[4]+red[6];
      ald[n*Hh+h]=red[1]+red[3]+red[5]+red[7];
    }
    __syncthreads();
  }
}

// per-edge alpha (valid edges only)
__global__ void gat_alpha(const int* __restrict__ src, const int* __restrict__ dst,
    const int* __restrict__ mask, const float* __restrict__ als, const float* __restrict__ ald,
    int E_, int Hh, float* __restrict__ alpha){
  int e = blockIdx.x*256+threadIdx.x;
  if (e>=E_ || !mask[e]) return;
  int s=src[e], d=dst[e];
  for (int h=0;h<Hh;h++){
    float a = als[s*Hh+h] + ald[d*Hh+h];
    alpha[(size_t)e*Hh+h] = a>0.f ? a : 0.2f*a;
  }
}

// block-per-node aggregation (softmax over incoming valid edges + self loop)
template<int Hh,int C,int ELU>
__global__ __launch_bounds__(256) void gat_agg(const int* __restrict__ src, const int* __restrict__ dst,
    const int* __restrict__ mask, const float* __restrict__ xp, const float* __restrict__ alpha,
    const float* __restrict__ als, const float* __restrict__ ald, const float* __restrict__ bias,
    int E_, float* __restrict__ outf, unsigned short* __restrict__ outb){
  constexpr int TOT = Hh*C;
  constexpr int Q = TOT/256;
  int n = blockIdx.x, t = threadIdx.x;
  __shared__ int list[1024];
  __shared__ int cnt;
  __shared__ float red[4];
  __shared__ float m_sh[Hh], d_sh[Hh];
  if (t==0) cnt=0;
  __syncthreads();
  for (int e=t;e<E_;e+=256)
    if (dst[e]==n && mask[e]){ int p=atomicAdd(&cnt,1); if (p<1024) list[p]=e; }
  __syncthreads();
  int KK = min(cnt,1024);
  float selfa[Hh];
  #pragma unroll
  for (int h=0;h<Hh;h++){ float a = als[n*Hh+h]+ald[n*Hh+h]; selfa[h] = a>0.f?a:0.2f*a; }
  // segment max
  #pragma unroll
  for (int h=0;h<Hh;h++){
    float mx = selfa[h];
    for (int i=t;i<KK;i+=256) mx = fmaxf(mx, alpha[(size_t)list[i]*Hh+h]);
    #pragma unroll
    for (int o=32;o>0;o>>=1) mx = fmaxf(mx, __shfl_down(mx,o));
    __syncthreads();
    if ((t&63)==0) red[t>>6]=mx;
    __syncthreads();
    if (t==0) m_sh[h]=fmaxf(fmaxf(red[0],red[1]),fmaxf(red[2],red[3]));
    __syncthreads();
  }
  // denom
  #pragma unroll
  for (int h=0;h<Hh;h++){
    float s = (t==0)? __expf(selfa[h]-m_sh[h]) : 0.f;
    for (int i=t;i<KK;i+=256) s += __expf(alpha[(size_t)list[i]*Hh+h]-m_sh[h]);
    #pragma unroll
    for (int o=32;o>0;o>>=1) s += __shfl_down(s,o);
    __syncthreads();
    if ((t&63)==0) red[t>>6]=s;
    __syncthreads();
    if (t==0) d_sh[h]=red[0]+red[1]+red[2]+red[3];
    __syncthreads();
  }
  // weighted aggregation
  float acc[Q];
  #pragma unroll
  for (int q=0;q<Q;q++){
    int cc=t+q*256; int h=cc/C;
    acc[q]=__expf(selfa[h]-m_sh[h])*xp[(size_t)n*TOT+cc];
  }
  for (int i=0;i<KK;i++){
    int e=list[i]; int sn=src[e];
    #pragma unroll
    for (int q=0;q<Q;q++){
      int cc=t+q*256; int h=cc/C;
      float w=__expf(alpha[(size_t)e*Hh+h]-m_sh[h]);
      acc[q] += w*xp[(size_t)sn*TOT+cc];
    }
  }
  #pragma unroll
  for (int q=0;q<Q;q++){
    int cc=t+q*256; int h=cc/C;
    float v = acc[q]/d_sh[h] + bias[cc];
    if (ELU) v = v>0.f ? v : __expf(v)-1.f;
    if (outf) outf[(size_t)n*TOT+cc]=v;
    if (outb) outb[(size_t)n*TOT+cc]=f2bf(v);
  }
}

// ---------------- edge features ----------------
__global__ void build_ef(const int* __restrict__ src, const int* __restrict__ dst,
                         const float* __restrict__ h2, unsigned short* __restrict__ ef){
  int e = blockIdx.x, c = threadIdx.x;
  float xi = h2[(size_t)src[e]*256+c];
  float xj = h2[(size_t)dst[e]*256+c];
  size_t b = (size_t)e*1024;
  ef[b+c]     = f2bf(xi);
  ef[b+256+c] = f2bf(xj);
  ef[b+512+c] = f2bf(fabsf(xi-xj));
  ef[b+768+c] = f2bf(xi*xj);
}

// ---------------- masked batch norm ----------------
__global__ void bn_part(const float* __restrict__ z, const int* __restrict__ mask,
                        int C, int chunk, float* __restrict__ ps, float* __restrict__ pq){
  int eb = blockIdx.x, c = threadIdx.x;   // blockDim == C
  float s=0.f,q=0.f;
  for (int i=0;i<chunk;i++){
    int e = eb*chunk+i;
    if (mask[e]){ float v=z[(size_t)e*C+c]; s+=v; q+=v*v; }
  }
  ps[eb*C+c]=s; pq[eb*C+c]=q;
}

__global__ void bn_stats(const float* __restrict__ ps, const float* __restrict__ pq,
                         int nP, int C, const int* __restrict__ cnt,
                         const float* __restrict__ g, const float* __restrict__ b,
                         float* __restrict__ scale, float* __restrict__ shift){
  int c = blockIdx.x*blockDim.x+threadIdx.x;
  if (c>=C) return;
  float s=0.f,q=0.f;
  for (int p=0;p<nP;p++){ s+=ps[p*C+c]; q+=pq[p*C+c]; }
  float cn = fmaxf((float)cnt[0], 1.f);
  float mean = s/cn;
  float var = fmaxf(q/cn - mean*mean, 0.f);
  float rstd = rsqrtf(var + 1e-5f);
  scale[c] = rstd*g[c];
  shift[c] = b[c] - mean*rstd*g[c];
}

__global__ void bn_norm(const float* __restrict__ z, const float* __restrict__ scale,
                        const float* __restrict__ shift, int total, int cmask,
                        float* __restrict__ outf, unsigned short* __restrict__ outb){
  int idx = blockIdx.x*256+threadIdx.x;
  if (idx>=total) return;
  int c = idx & cmask;
  float v = fmaxf(z[idx]*scale[c]+shift[c], 0.f);
  if (outf) outf[idx]=v;
  else outb[idx]=f2bf(v);
}

// ---------------- final score ----------------
__global__ void final_score(const float* __restrict__ z, const float* __restrict__ w,
                            const float* __restrict__ b, const int* __restrict__ mask,
                            float* __restrict__ out, int E_){
  int wv = threadIdx.x>>6, lane = threadIdx.x&63;
  int e = blockIdx.x*4+wv;
  if (e>=E_) return;
  float s = z[(size_t)e*128+lane]*w[lane] + z[(size_t)e*128+64+lane]*w[64+lane];
  #pragma unroll
  for (int o=32;o>0;o>>=1) s += __shfl_down(s,o);
  if (lane==0){
    float logit = mask[e] ? (s+b[0]) : -2.5f;
    out[e] = 1.f/(1.f+__expf(-logit));
  }
}

// ---------------- launch ----------------
extern "C" void kernel_launch(void* const* d_in, const int* in_sizes, int n_in,
                              void* d_out, int out_size, void* d_ws, size_t ws_size,
                              hipStream_t stream) {
  const float* x      = (const float*)d_in[0];
  const int*   ei     = (const int*)d_in[1];
  const float* semb   = (const float*)d_in[2];
  const float* elp    = (const float*)d_in[3];
  const float* fc0_w  = (const float*)d_in[4];  const float* fc0_b = (const float*)d_in[5];
  const float* fcl_w  = (const float*)d_in[6];  const float* fcl_b = (const float*)d_in[7];
  const float* fce_w  = (const float*)d_in[8];  const float* fce_b = (const float*)d_in[9];
  const float* fc2_w  = (const float*)d_in[10]; const float* fc2_b = (const float*)d_in[11];
  const float* fc1_w  = (const float*)d_in[12]; const float* fc1_b = (const float*)d_in[13];
  const float* c1W    = (const float*)d_in[14]; const float* c1as  = (const float*)d_in[15];
  const float* c1ad   = (const float*)d_in[16]; const float* c1b   = (const float*)d_in[17];
  const float* c2W    = (const float*)d_in[18]; const float* c2as  = (const float*)d_in[19];
  const float* c2ad   = (const float*)d_in[20]; const float* c2b   = (const float*)d_in[21];
  const float* m1w    = (const float*)d_in[22]; const float* m1b   = (const float*)d_in[23];
  const float* bn1g   = (const float*)d_in[24]; const float* bn1b  = (const float*)d_in[25];
  const float* m2w    = (const float*)d_in[26]; const float* m2b   = (const float*)d_in[27];
  const float* bn2g   = (const float*)d_in[28]; const float* bn2b  = (const float*)d_in[29];
  const float* m3w    = (const float*)d_in[30]; const float* m3b   = (const float*)d_in[31];
  float* out = (float*)d_out;
  const int E_ = 8192;
  const int* srcp = ei;
  const int* dstp = ei + E_;

  char* wsb = (char*)d_ws; size_t off = 0;
  auto alloc = [&](size_t bytes)->char*{ char* p = wsb+off; off += (bytes+255)&~(size_t)255; return p; };

  float*  cat   = (float*)alloc(16384*4);
  float*  sentv = (float*)alloc(512*4);
  float*  pg1   = (float*)alloc((size_t)64*8192*4);
  float*  pg2   = (float*)alloc((size_t)12*8192*4);
  float*  psent = (float*)alloc((size_t)6*512*4);
  double* pfc2  = (double*)alloc((size_t)128*8192*8);
  int*    maskp = (int*)alloc(8192*4);
  int*    cntp  = (int*)alloc(256);
  unsigned short* xbf  = (unsigned short*)alloc((size_t)2048*256*2);
  unsigned short* fc1t = (unsigned short*)alloc((size_t)512*256*2);
  unsigned short* c1t  = (unsigned short*)alloc((size_t)1024*512*2);
  unsigned short* c2t  = (unsigned short*)alloc((size_t)256*1024*2);
  unsigned short* m1t  = (unsigned short*)alloc((size_t)256*1024*2);
  unsigned short* m2t  = (unsigned short*)alloc((size_t)128*256*2);
  unsigned short* h0   = (unsigned short*)alloc((size_t)2048*512*2);
  float*  xp1   = (float*)alloc((size_t)2048*1024*4);
  float*  als1  = (float*)alloc(2048*4*4);
  float*  ald1  = (float*)alloc(2048*4*4);
  float*  alpha1= (float*)alloc((size_t)8192*4*4);
  unsigned short* h1 = (unsigned short*)alloc((size_t)2048*1024*2);
  float*  xp2   = (float*)alloc((size_t)2048*256*4);
  float*  als2  = (float*)alloc(2048*4);
  float*  ald2  = (float*)alloc(2048*4);
  float*  alpha2= (float*)alloc(8192*4);
  float*  h2    = (float*)alloc((size_t)2048*256*4);
  unsigned short* ef = (unsigned short*)alloc((size_t)8192*1024*2);
  float*  z1    = (float*)alloc((size_t)8192*256*4);
  float*  bps1  = (float*)alloc(64*256*4);
  float*  bpq1  = (float*)alloc(64*256*4);
  float*  bsc1  = (float*)alloc(256*4);
  float*  bsh1  = (float*)alloc(256*4);
  unsigned short* z1b = (unsigned short*)alloc((size_t)8192*256*2);
  float*  z2    = (float*)alloc((size_t)8192*128*4);
  float*  bps2  = (float*)alloc(64*128*4);
  float*  bpq2  = (float*)alloc(64*128*4);
  float*  bsc2  = (float*)alloc(128*4);
  float*  bsh2  = (float*)alloc(128*4);
  float*  z2b   = (float*)alloc((size_t)8192*128*4);

  // weight conversions (independent of data path)
  k_transpose_bf16<<<(256*512+255)/256,256,0,stream>>>(fc1_w, fc1t, 256, 512);
  k_transpose_bf16<<<(512*1024+255)/256,256,0,stream>>>(c1W, c1t, 512, 1024);
  k_transpose_bf16<<<(1024*256+255)/256,256,0,stream>>>(c2W, c2t, 1024, 256);
  k_transpose_bf16<<<(1024*256+255)/256,256,0,stream>>>(m1w, m1t, 1024, 256);
  k_transpose_bf16<<<(256*128+255)/256,256,0,stream>>>(m2w, m2t, 256, 128);
  k_f32_to_bf16<<<(2048*256+255)/256,256,0,stream>>>(x, xbf, 2048*256);

  // sent = relu(semb @ fc0_w + fc0_b)
  matvec_part_f32<<<dim3(1,6),128,0,stream>>>(semb, fc0_w, 512, 128, psent);
  matvec_reduce_relu<<<2,256,0,stream>>>(psent, 6, 512, fc0_b, sentv);
  // g1 = relu(elp @ fcl_w + fcl_b)
  matvec_part_f32<<<dim3(8,64),256,0,stream>>>(elp, fcl_w, 8192, 128, pg1);
  matvec_reduce_relu<<<32,256,0,stream>>>(pg1, 64, 8192, fcl_b, cat);
  // g2 = relu(semb @ fce_w + fce_b)
  matvec_part_f32<<<dim3(8,12),256,0,stream>>>(semb, fce_w, 8192, 64, pg2);
  matvec_reduce_relu<<<32,256,0,stream>>>(pg2, 12, 8192, fce_b, cat+8192);
  // orig = cat @ fc2_w + fc2_b  (fp64 accumulation for mask stability)
  matvec_part_f64<<<dim3(8,128),256,0,stream>>>(cat, fc2_w, 8192, 128, pfc2);
  hipMemsetAsync(cntp, 0, sizeof(int), stream);
  fc2_reduce<<<32,256,0,stream>>>(pfc2, 128, 8192, fc2_b, out+8192, maskp, cntp);

  // h0 = relu(x@fc1 + b) + sent  -> bf16
  gemm_bt<128,128,2><<<dim3(16,4),256,0,stream>>>(xbf, fc1t, 2048,512,256, fc1_b, sentv, nullptr, h0);
  // conv1: xp1 = h0 @ conv1_W
  gemm_bt<128,128,0><<<dim3(16,8),256,0,stream>>>(h0, c1t, 2048,1024,512, nullptr, nullptr, xp1, nullptr);
  gat_al<<<2048,256,0,stream>>>(xp1, c1as, c1ad, 4, 256, als1, ald1);
  gat_alpha<<<32,256,0,stream>>>(srcp,dstp,maskp, als1, ald1, E_, 4, alpha1);
  gat_agg<4,256,1><<<2048,256,0,stream>>>(srcp,dstp,maskp, xp1, alpha1, als1, ald1, c1b, E_, nullptr, h1);
  // conv2
  gemm_bt<128,128,0><<<dim3(16,2),256,0,stream>>>(h1, c2t, 2048,256,1024, nullptr, nullptr, xp2, nullptr);
  gat_al<<<2048,256,0,stream>>>(xp2, c2as, c2ad, 1, 256, als2, ald2);
  gat_alpha<<<32,256,0,stream>>>(srcp,dstp,maskp, als2, ald2, E_, 1, alpha2);
  gat_agg<1,256,0><<<2048,256,0,stream>>>(srcp,dstp,maskp, xp2, alpha2, als2, ald2, c2b, E_, h2, nullptr);
  // edge MLP
  build_ef<<<8192,256,0,stream>>>(srcp,dstp,h2,ef);
  gemm_bt<128,128,1><<<dim3(64,2),256,0,stream>>>(ef, m1t, 8192,256,1024, m1b, nullptr, z1, nullptr);
  bn_part<<<64,256,0,stream>>>(z1, maskp, 256, 128, bps1, bpq1);
  bn_stats<<<1,256,0,stream>>>(bps1,bpq1,64,256,cntp,bn1g,bn1b,bsc1,bsh1);
  bn_norm<<<8192,256,0,stream>>>(z1,bsc1,bsh1, 8192*256, 255, nullptr, z1b);
  gemm_bt<128,128,1><<<dim3(64,1),256,0,stream>>>(z1b, m2t, 8192,128,256, m2b, nullptr, z2, nullptr);
  bn_part<<<64,128,0,stream>>>(z2, maskp, 128, 128, bps2, bpq2);
  bn_stats<<<1,128,0,stream>>>(bps2,bpq2,64,128,cntp,bn2g,bn2b,bsc2,bsh2);
  bn_norm<<<4096,256,0,stream>>>(z2,bsc2,bsh2, 8192*128, 127, z2b, nullptr);
  final_score<<<2048,256,0,stream>>>(z2b, m3w, m3b, maskp, out, E_);
}